// Round 5
// baseline (891.306 us; speedup 1.0000x reference)
//
#include <hip/hip_runtime.h>

typedef _Float16 half8 __attribute__((ext_vector_type(8)));
typedef unsigned short ushort8 __attribute__((ext_vector_type(8)));
typedef float floatx4 __attribute__((ext_vector_type(4)));
typedef unsigned short u16;

#define NROWS 115200
#define MT 32

__device__ __forceinline__ void splitf(float f, u16& hi, u16& lo) {
    _Float16 h = (_Float16)f;
    _Float16 l = (_Float16)(f - (float)h);
    hi = __builtin_bit_cast(u16, h);
    lo = __builtin_bit_cast(u16, l);
}

// swizzled index into a [MT][256] fp16 LDS plane (16B-block XOR swizzle)
__device__ __forceinline__ int swz(int row, int col) {
    return row * 256 + ((((col >> 3)) ^ (row & 31)) << 3) + (col & 7);
}

// Pack src[K][N] fp32 into fragment-major split-fp16 planes:
// dst[((nt*kfrags + kf)*16 + m)*8 + j] = src[kf*8+j][nt*16+m]
__global__ void prep_pack(const float* __restrict__ src, u16* __restrict__ dhi,
                          u16* __restrict__ dlo, int K, int N, int Kd) {
    int kfrags = Kd >> 3;
    int nt = blockIdx.y;
    int frag = blockIdx.x * blockDim.x + threadIdx.x;
    if (frag >= kfrags * 16) return;
    int kf = frag >> 4, m = frag & 15;
    int n = nt * 16 + m;
    ushort8 vh, vl;
    #pragma unroll
    for (int j = 0; j < 8; ++j) {
        int k = kf * 8 + j;
        float v = (k < K && n < N) ? src[(size_t)k * N + n] : 0.f;
        u16 hi, lo; splitf(v, hi, lo);
        vh[j] = hi; vl[j] = lo;
    }
    size_t o = ((size_t)nt * kfrags + kf) * 128 + (size_t)m * 8;
    *(ushort8*)&dhi[o] = vh;
    *(ushort8*)&dlo[o] = vl;
}

// Fused: W23 = W2 @ W3 (sequential-j fmaf, bit-identical to previous w23_gemm)
// and pack split-fp16 planes directly + b23 = b3 + b2 @ W3.
// grid (2, 10), 256 threads. Block (bx, nt): frags kf = bx*16 + t>>4, m = t&15.
__global__ void prep_w23(const float* __restrict__ W2, const float* __restrict__ W3,
                         const float* __restrict__ b2, const float* __restrict__ b3,
                         u16* __restrict__ dhi, u16* __restrict__ dlo,
                         float* __restrict__ b23) {
    __shared__ float w3c[256][17];   // W3 column tile, +1 pad
    int nt = blockIdx.y;
    int t = threadIdx.x;
    // stage W3[:, nt*16 .. nt*16+15] (zero-padded past col 156)
    #pragma unroll
    for (int c = 0; c < 16; ++c) {
        int n = nt * 16 + c;
        w3c[t][c] = (n < 157) ? W3[(size_t)t * 157 + n] : 0.f;
    }
    __syncthreads();

    int frag = blockIdx.x * 256 + t;
    int kf = frag >> 4, m = frag & 15;
    int n = nt * 16 + m;

    // b23 (block bx==0, kf==0 threads): same fmaf order as before
    if (blockIdx.x == 0 && kf == 0 && n < 157) {
        float bb = b3[n];
        for (int j = 0; j < 256; ++j) bb = fmaf(b2[j], w3c[j][m], bb);
        b23[n] = bb;
    }

    ushort8 vh, vl;
    #pragma unroll
    for (int j = 0; j < 8; ++j) {
        int k = kf * 8 + j;
        const float* w2r = W2 + (size_t)k * 256;
        float acc = 0.f;
        for (int jj = 0; jj < 256; ++jj)
            acc = fmaf(w2r[jj], w3c[jj][m], acc);
        u16 hi, lo; splitf(acc, hi, lo);
        vh[j] = hi; vl[j] = lo;
    }
    size_t o = ((size_t)nt * 32 + kf) * 128 + (size_t)m * 8;
    *(ushort8*)&dhi[o] = vh;
    *(ushort8*)&dlo[o] = vl;
}

// 512 threads = 8 waves; 53KB LDS -> 3 blocks/CU -> 6 waves/SIMD.
// hx = x@W1x hoisted (x iteration-invariant); x planes die after hx and the
// same region hosts the h planes; theta has its own region -> 2 barriers/iter.
__global__ __launch_bounds__(512, 6) void fused_head(
    const float* __restrict__ xg,
    const u16* __restrict__ w1h, const u16* __restrict__ w1l,
    const u16* __restrict__ w23h, const u16* __restrict__ w23l,
    const float* __restrict__ b1g, const float* __restrict__ b23g,
    const float* __restrict__ ipose, const float* __restrict__ ishape, const float* __restrict__ icam,
    float* __restrict__ out)
{
    // 54272 B = exactly 53 KB static LDS
    __shared__ __align__(16) u16 smem[27136];
    u16* P0  = smem;                  // x hi plane (prologue) -> h1 hi plane (loop)
    u16* P1  = smem + 8192;           // x lo plane (prologue) -> h1 lo plane (loop)
    u16* tsh = smem + 16384;          // theta hi [32][168]
    u16* tsl = smem + 21760;          // theta lo [32][168]
    float* thf = (float*)smem;        // [32][144] fp32 pose (final; overlays h planes)

    const int t = threadIdx.x;
    const int lid = t & 63, wv = t >> 6;       // 8 waves
    const int q = lid >> 4, m = lid & 15;      // quad, lane-in-16
    const int fb = q * 128 + m * 8;            // fragment-local B offset
    const long rowbase = (long)blockIdx.x * MT;

    // ---- stage x tile (32 rows x 256 fp32 -> split fp16 planes) ----
    #pragma unroll
    for (int i = 0; i < 2; ++i) {
        int idx = t + i * 512;
        int r = idx >> 5, s = idx & 31;
        const float4* sp = (const float4*)(xg + (rowbase + r) * 256 + s * 8);
        float4 f0 = sp[0], f1 = sp[1];
        float fv[8] = {f0.x, f0.y, f0.z, f0.w, f1.x, f1.y, f1.z, f1.w};
        ushort8 vh, vl;
        #pragma unroll
        for (int j = 0; j < 8; ++j) {
            u16 hi, lo; splitf(fv[j], hi, lo);
            vh[j] = hi; vl[j] = lo;
        }
        int o = r * 256 + ((s ^ (r & 31)) << 3);
        *(ushort8*)&P0[o] = vh;
        *(ushort8*)&P1[o] = vl;
    }

    // ---- theta fp32 master in registers (GEMM23 C-frag layout) ----
    // column tile for (wv,c) = wv + c*8; valid tiles 0..9
    const int ncts = (wv < 2) ? 2 : 1;
    float tm[2][2][4];
    #pragma unroll
    for (int c = 0; c < 2; ++c) {
        int n3 = (wv + c * 8) * 16 + m;
        float v;
        if (n3 < 144)      v = ipose[n3];
        else if (n3 < 154) v = ishape[n3 - 144];
        else if (n3 < 157) v = icam[n3 - 154];
        else               v = 0.f;
        #pragma unroll
        for (int rt = 0; rt < 2; ++rt)
            #pragma unroll
            for (int r = 0; r < 4; ++r) tm[c][rt][r] = v;
    }
    // ---- theta0 -> tsh/tsl (disjoint region; no barrier needed yet) ----
    #pragma unroll
    for (int c = 0; c < 2; ++c) {
        if (c < ncts) {
            int n3 = (wv + c * 8) * 16 + m;
            #pragma unroll
            for (int rt = 0; rt < 2; ++rt)
                #pragma unroll
                for (int r = 0; r < 4; ++r) {
                    int row = rt * 16 + q * 4 + r;
                    u16 hi, lo; splitf(tm[c][rt][r], hi, lo);
                    tsh[row * 168 + n3] = hi;
                    tsl[row * 168 + n3] = lo;
                }
        }
    }
    __syncthreads();   // x planes + theta0 visible

    const floatx4 zero4 = {0.f, 0.f, 0.f, 0.f};

    // ============ hoisted: hx = x @ W1x  (K=256, once) ============
    floatx4 hx[2][2];
    #pragma unroll
    for (int ct = 0; ct < 2; ++ct)
        #pragma unroll
        for (int rt = 0; rt < 2; ++rt) hx[ct][rt] = zero4;

    #pragma unroll 2
    for (int ks = 0; ks < 8; ++ks) {
        half8 ah[2], al[2];
        #pragma unroll
        for (int rt = 0; rt < 2; ++rt) {
            int o = swz(rt * 16 + m, ks * 32 + q * 8);
            ah[rt] = *(const half8*)&P0[o];
            al[rt] = *(const half8*)&P1[o];
        }
        int bbase = wv * 13312 + ks * 512 + fb;
        #pragma unroll
        for (int ct = 0; ct < 2; ++ct) {
            half8 bh = *(const half8*)(w1h + bbase + ct * 6656);
            half8 bl = *(const half8*)(w1l + bbase + ct * 6656);
            #pragma unroll
            for (int rt = 0; rt < 2; ++rt) {
                hx[ct][rt] = __builtin_amdgcn_mfma_f32_16x16x32_f16(ah[rt], bh, hx[ct][rt], 0, 0, 0);
                hx[ct][rt] = __builtin_amdgcn_mfma_f32_16x16x32_f16(al[rt], bh, hx[ct][rt], 0, 0, 0);
                hx[ct][rt] = __builtin_amdgcn_mfma_f32_16x16x32_f16(ah[rt], bl, hx[ct][rt], 0, 0, 0);
            }
        }
    }
    __syncthreads();   // all x-plane reads done -> region hosts h planes now

    for (int it = 0; it < 3; ++it) {
        // ===== GEMM1 theta-part: acc = hx + theta @ W1t, K=160 =====
        floatx4 acc[2][2];
        #pragma unroll
        for (int ct = 0; ct < 2; ++ct)
            #pragma unroll
            for (int rt = 0; rt < 2; ++rt) acc[ct][rt] = hx[ct][rt];

        #pragma unroll 1
        for (int ks = 8; ks < 13; ++ks) {
            int kp = (ks - 8) * 32 + q * 8;
            half8 ah[2], al[2];
            #pragma unroll
            for (int rt = 0; rt < 2; ++rt) {
                int o = (rt * 16 + m) * 168 + kp;
                ah[rt] = *(const half8*)&tsh[o];
                al[rt] = *(const half8*)&tsl[o];
            }
            int bbase = wv * 13312 + ks * 512 + fb;
            #pragma unroll
            for (int ct = 0; ct < 2; ++ct) {
                half8 bh = *(const half8*)(w1h + bbase + ct * 6656);
                half8 bl = *(const half8*)(w1l + bbase + ct * 6656);
                #pragma unroll
                for (int rt = 0; rt < 2; ++rt) {
                    acc[ct][rt] = __builtin_amdgcn_mfma_f32_16x16x32_f16(ah[rt], bh, acc[ct][rt], 0, 0, 0);
                    acc[ct][rt] = __builtin_amdgcn_mfma_f32_16x16x32_f16(al[rt], bh, acc[ct][rt], 0, 0, 0);
                    acc[ct][rt] = __builtin_amdgcn_mfma_f32_16x16x32_f16(ah[rt], bl, acc[ct][rt], 0, 0, 0);
                }
            }
        }
        // epi: bias + relu -> h planes (x region; safe: x dead, prev-iter h
        // readers all passed last barrier)
        #pragma unroll
        for (int ct = 0; ct < 2; ++ct) {
            int n = wv * 32 + ct * 16 + m;
            float bv = b1g[n];
            #pragma unroll
            for (int rt = 0; rt < 2; ++rt)
                #pragma unroll
                for (int r = 0; r < 4; ++r) {
                    int row = rt * 16 + q * 4 + r;
                    float v = fmaxf(acc[ct][rt][r] + bv, 0.f);
                    u16 hi, lo; splitf(v, hi, lo);
                    int o = swz(row, n);
                    P0[o] = hi; P1[o] = lo;
                }
        }
        __syncthreads();   // A: h1 visible; all theta reads of this iter done

        // ======== GEMM23: theta += h1 @ (W2@W3) + b23, K=256, N=160(pad) ========
        floatx4 a3[2][2];
        #pragma unroll
        for (int c = 0; c < 2; ++c)
            #pragma unroll
            for (int rt = 0; rt < 2; ++rt) a3[c][rt] = zero4;

        #pragma unroll 2
        for (int ks = 0; ks < 8; ++ks) {
            half8 ah[2], al[2];
            #pragma unroll
            for (int rt = 0; rt < 2; ++rt) {
                int o = swz(rt * 16 + m, ks * 32 + q * 8);
                ah[rt] = *(const half8*)&P0[o];
                al[rt] = *(const half8*)&P1[o];
            }
            int bbase = ks * 512 + fb;
            #pragma unroll
            for (int c = 0; c < 2; ++c) {
                if (c < ncts) {
                    half8 bh = *(const half8*)(w23h + bbase + (wv + c * 8) * 4096);
                    half8 bl = *(const half8*)(w23l + bbase + (wv + c * 8) * 4096);
                    #pragma unroll
                    for (int rt = 0; rt < 2; ++rt) {
                        a3[c][rt] = __builtin_amdgcn_mfma_f32_16x16x32_f16(ah[rt], bh, a3[c][rt], 0, 0, 0);
                        a3[c][rt] = __builtin_amdgcn_mfma_f32_16x16x32_f16(al[rt], bh, a3[c][rt], 0, 0, 0);
                        a3[c][rt] = __builtin_amdgcn_mfma_f32_16x16x32_f16(ah[rt], bl, a3[c][rt], 0, 0, 0);
                    }
                }
            }
        }
        // fp32 residual update of theta master
        #pragma unroll
        for (int c = 0; c < 2; ++c) {
            if (c < ncts) {
                int n3 = (wv + c * 8) * 16 + m;
                float b3v = (n3 < 157) ? b23g[n3] : 0.f;
                #pragma unroll
                for (int rt = 0; rt < 2; ++rt)
                    #pragma unroll
                    for (int r = 0; r < 4; ++r)
                        tm[c][rt][r] += a3[c][rt][r] + b3v;
            }
        }

        if (it < 2) {
            // restage theta (own region; this iter's theta readers finished
            // before sync A)
            #pragma unroll
            for (int c = 0; c < 2; ++c) {
                if (c < ncts) {
                    int n3 = (wv + c * 8) * 16 + m;
                    #pragma unroll
                    for (int rt = 0; rt < 2; ++rt)
                        #pragma unroll
                        for (int r = 0; r < 4; ++r) {
                            int row = rt * 16 + q * 4 + r;
                            u16 hi, lo; splitf(tm[c][rt][r], hi, lo);
                            tsh[row * 168 + n3] = hi;
                            tsl[row * 168 + n3] = lo;
                        }
                }
            }
            __syncthreads();   // B: theta' visible; all GEMM23 h reads done
        } else {
            __syncthreads();   // B: all GEMM23 h reads done -> thf may overlay h
            // final: pose -> fp32 LDS (overlays h planes); betas/camera -> global
            #pragma unroll
            for (int c = 0; c < 2; ++c) {
                if (c < ncts) {
                    int tile = wv + c * 8;
                    int n3 = tile * 16 + m;
                    if (tile < 9) {
                        #pragma unroll
                        for (int rt = 0; rt < 2; ++rt)
                            #pragma unroll
                            for (int r = 0; r < 4; ++r) {
                                int row = rt * 16 + q * 4 + r;
                                thf[row * 144 + n3] = tm[c][rt][r];
                            }
                    } else {  // tile 9: cols 144..159 = betas + camera
                        #pragma unroll
                        for (int rt = 0; rt < 2; ++rt)
                            #pragma unroll
                            for (int r = 0; r < 4; ++r) {
                                int row = rt * 16 + q * 4 + r;
                                long grow = rowbase + row;
                                float v = tm[c][rt][r];
                                if (m < 10)
                                    out[(size_t)NROWS * 216 + grow * 10 + m] = v;
                                else if (m < 13)
                                    out[(size_t)NROWS * 216 + (size_t)NROWS * 10 + grow * 3 + (m - 10)] = v;
                            }
                    }
                }
            }
            __syncthreads();   // thf visible
        }
    }

    // ============ epilogue: rot6d -> rotmat (fp32), 8 threads/row ============
    if (t < 256) {
        int r = t >> 3, g = t & 7;     // 8 threads per row, 3 consecutive joints each
        long grow = rowbase + r;
        #pragma unroll
        for (int jj = 0; jj < 3; ++jj) {
            int j = g * 3 + jj;
            const float* p = &thf[r * 144 + j * 6];
            float a1x = p[0], a2x = p[1], a1y = p[2], a2y = p[3], a1z = p[4], a2z = p[5];
            float n1 = fmaxf(sqrtf(a1x * a1x + a1y * a1y + a1z * a1z), 1e-12f);
            float b1x = a1x / n1, b1y = a1y / n1, b1z = a1z / n1;
            float d = b1x * a2x + b1y * a2y + b1z * a2z;
            float ux = a2x - d * b1x, uy = a2y - d * b1y, uz = a2z - d * b1z;
            float n2 = fmaxf(sqrtf(ux * ux + uy * uy + uz * uz), 1e-12f);
            float b2x = ux / n2, b2y = uy / n2, b2z = uz / n2;
            float b3x = b1y * b2z - b1z * b2y;
            float b3y = b1z * b2x - b1x * b2z;
            float b3z = b1x * b2y - b1y * b2x;
            float* o = out + (size_t)grow * 216 + j * 9;
            o[0] = b1x; o[1] = b2x; o[2] = b3x;
            o[3] = b1y; o[4] = b2y; o[5] = b3y;
            o[6] = b1z; o[7] = b2z; o[8] = b3z;
        }
    }
}

extern "C" void kernel_launch(void* const* d_in, const int* in_sizes, int n_in,
                              void* d_out, int out_size, void* d_ws, size_t ws_size,
                              hipStream_t stream) {
    const float* x  = (const float*)d_in[0];
    const float* W1 = (const float*)d_in[2];
    const float* b1 = (const float*)d_in[3];
    const float* W2 = (const float*)d_in[4];
    const float* b2 = (const float*)d_in[5];
    const float* W3 = (const float*)d_in[6];
    const float* b3 = (const float*)d_in[7];
    const float* ip = (const float*)d_in[8];
    const float* is = (const float*)d_in[9];
    const float* ic = (const float*)d_in[10];

    u16* w1h  = (u16*)d_ws;               // 16 nt * 52 kf * 128 = 106496
    u16* w1l  = w1h + 106496;
    u16* w23h = w1l + 106496;             // 10 nt * 32 kf * 128 = 40960
    u16* w23l = w23h + 40960;
    float* b23f = (float*)(w23l + 40960); // 157 fp32

    prep_pack<<<dim3(4, 16), 256, 0, stream>>>(W1, w1h, w1l, 413, 256, 416);
    prep_w23<<<dim3(2, 10), 256, 0, stream>>>(W2, W3, b2, b3, w23h, w23l, b23f);

    fused_head<<<NROWS / MT, 512, 0, stream>>>(x, w1h, w1l, w23h, w23l,
                                               b1, b23f, ip, is, ic, (float*)d_out);
}

// Round 6
// 610.203 us; speedup vs baseline: 1.4607x; 1.4607x over previous
//
#include <hip/hip_runtime.h>

typedef _Float16 half8 __attribute__((ext_vector_type(8)));
typedef unsigned short ushort8 __attribute__((ext_vector_type(8)));
typedef float floatx4 __attribute__((ext_vector_type(4)));
typedef unsigned short u16;

#define NROWS 115200
#define MT 32

__device__ __forceinline__ void splitf(float f, u16& hi, u16& lo) {
    _Float16 h = (_Float16)f;
    _Float16 l = (_Float16)(f - (float)h);
    hi = __builtin_bit_cast(u16, h);
    lo = __builtin_bit_cast(u16, l);
}

// swizzled index into a [MT][256] fp16 LDS plane (16B-block XOR swizzle)
__device__ __forceinline__ int swz(int row, int col) {
    return row * 256 + ((((col >> 3)) ^ (row & 31)) << 3) + (col & 7);
}

// Pack src[K][N] fp32 into fragment-major split-fp16 planes:
// dst[((nt*kfrags + kf)*16 + m)*8 + j] = src[kf*8+j][nt*16+m]
__global__ void prep_pack(const float* __restrict__ src, u16* __restrict__ dhi,
                          u16* __restrict__ dlo, int K, int N, int Kd) {
    int kfrags = Kd >> 3;
    int nt = blockIdx.y;
    int frag = blockIdx.x * blockDim.x + threadIdx.x;
    if (frag >= kfrags * 16) return;
    int kf = frag >> 4, m = frag & 15;
    int n = nt * 16 + m;
    ushort8 vh, vl;
    #pragma unroll
    for (int j = 0; j < 8; ++j) {
        int k = kf * 8 + j;
        float v = (k < K && n < N) ? src[(size_t)k * N + n] : 0.f;
        u16 hi, lo; splitf(v, hi, lo);
        vh[j] = hi; vl[j] = lo;
    }
    size_t o = ((size_t)nt * kfrags + kf) * 128 + (size_t)m * 8;
    *(ushort8*)&dhi[o] = vh;
    *(ushort8*)&dlo[o] = vl;
}

// Fused: W23 = W2 @ W3 (sequential-j fmaf) packed to split-fp16 planes,
// plus b23 = b3 + b2 @ W3.
__global__ void prep_w23(const float* __restrict__ W2, const float* __restrict__ W3,
                         const float* __restrict__ b2, const float* __restrict__ b3,
                         u16* __restrict__ dhi, u16* __restrict__ dlo,
                         float* __restrict__ b23) {
    __shared__ float w3c[256][17];   // W3 column tile, +1 pad
    int nt = blockIdx.y;
    int t = threadIdx.x;
    #pragma unroll
    for (int c = 0; c < 16; ++c) {
        int n = nt * 16 + c;
        w3c[t][c] = (n < 157) ? W3[(size_t)t * 157 + n] : 0.f;
    }
    __syncthreads();

    int frag = blockIdx.x * 256 + t;
    int kf = frag >> 4, m = frag & 15;
    int n = nt * 16 + m;

    if (blockIdx.x == 0 && kf == 0 && n < 157) {
        float bb = b3[n];
        for (int j = 0; j < 256; ++j) bb = fmaf(b2[j], w3c[j][m], bb);
        b23[n] = bb;
    }

    ushort8 vh, vl;
    #pragma unroll
    for (int j = 0; j < 8; ++j) {
        int k = kf * 8 + j;
        const float* w2r = W2 + (size_t)k * 256;
        float acc = 0.f;
        for (int jj = 0; jj < 256; ++jj)
            acc = fmaf(w2r[jj], w3c[jj][m], acc);
        u16 hi, lo; splitf(acc, hi, lo);
        vh[j] = hi; vl[j] = lo;
    }
    size_t o = ((size_t)nt * 32 + kf) * 128 + (size_t)m * 8;
    *(ushort8*)&dhi[o] = vh;
    *(ushort8*)&dlo[o] = vl;
}

// 512 threads = 8 waves. NOTE (measured r0-r5): on this toolchain the 2nd
// __launch_bounds__ arg behaves as min BLOCKS per CU (CUDA semantics):
// (512,4) capped VGPR at exactly 64, (512,6) at 40 -> both spilled.
// (512,2) -> cap 128: natural ~90-110 VGPR, no spill; 2 blocks/CU.
__global__ __launch_bounds__(512, 2) void fused_head(
    const float* __restrict__ xg,
    const u16* __restrict__ w1h, const u16* __restrict__ w1l,
    const u16* __restrict__ w23h, const u16* __restrict__ w23l,
    const float* __restrict__ b1g, const float* __restrict__ b23g,
    const float* __restrict__ ipose, const float* __restrict__ ishape, const float* __restrict__ icam,
    float* __restrict__ out)
{
    // 54272 B static LDS
    __shared__ __align__(16) u16 smem[27136];
    u16* P0  = smem;                  // x hi plane (prologue) -> h1 hi plane (loop)
    u16* P1  = smem + 8192;           // x lo plane (prologue) -> h1 lo plane (loop)
    u16* tsh = smem + 16384;          // theta hi [32][168]
    u16* tsl = smem + 21760;          // theta lo [32][168]
    float* thf = (float*)smem;        // [32][144] fp32 pose (final; overlays h planes)

    const int t = threadIdx.x;
    const int lid = t & 63, wv = t >> 6;       // 8 waves
    const int q = lid >> 4, m = lid & 15;      // quad, lane-in-16
    const int fb = q * 128 + m * 8;            // fragment-local B offset
    const long rowbase = (long)blockIdx.x * MT;

    // ---- stage x tile (32 rows x 256 fp32 -> split fp16 planes) ----
    #pragma unroll
    for (int i = 0; i < 2; ++i) {
        int idx = t + i * 512;
        int r = idx >> 5, s = idx & 31;
        const float4* sp = (const float4*)(xg + (rowbase + r) * 256 + s * 8);
        float4 f0 = sp[0], f1 = sp[1];
        float fv[8] = {f0.x, f0.y, f0.z, f0.w, f1.x, f1.y, f1.z, f1.w};
        ushort8 vh, vl;
        #pragma unroll
        for (int j = 0; j < 8; ++j) {
            u16 hi, lo; splitf(fv[j], hi, lo);
            vh[j] = hi; vl[j] = lo;
        }
        int o = r * 256 + ((s ^ (r & 31)) << 3);
        *(ushort8*)&P0[o] = vh;
        *(ushort8*)&P1[o] = vl;
    }

    // ---- theta fp32 master in registers (GEMM23 C-frag layout) ----
    // column tile for (wv,c) = wv + c*8; valid tiles 0..9
    const int ncts = (wv < 2) ? 2 : 1;
    float tm[2][2][4];
    #pragma unroll
    for (int c = 0; c < 2; ++c) {
        int n3 = (wv + c * 8) * 16 + m;
        float v;
        if (n3 < 144)      v = ipose[n3];
        else if (n3 < 154) v = ishape[n3 - 144];
        else if (n3 < 157) v = icam[n3 - 154];
        else               v = 0.f;
        #pragma unroll
        for (int rt = 0; rt < 2; ++rt)
            #pragma unroll
            for (int r = 0; r < 4; ++r) tm[c][rt][r] = v;
    }
    // ---- theta0 -> tsh/tsl (disjoint region) ----
    #pragma unroll
    for (int c = 0; c < 2; ++c) {
        if (c < ncts) {
            int n3 = (wv + c * 8) * 16 + m;
            #pragma unroll
            for (int rt = 0; rt < 2; ++rt)
                #pragma unroll
                for (int r = 0; r < 4; ++r) {
                    int row = rt * 16 + q * 4 + r;
                    u16 hi, lo; splitf(tm[c][rt][r], hi, lo);
                    tsh[row * 168 + n3] = hi;
                    tsl[row * 168 + n3] = lo;
                }
        }
    }
    __syncthreads();   // x planes + theta0 visible

    const floatx4 zero4 = {0.f, 0.f, 0.f, 0.f};

    // ============ hoisted: hx = x @ W1x  (K=256, once) ============
    floatx4 hx[2][2];
    #pragma unroll
    for (int ct = 0; ct < 2; ++ct)
        #pragma unroll
        for (int rt = 0; rt < 2; ++rt) hx[ct][rt] = zero4;

    #pragma unroll 2
    for (int ks = 0; ks < 8; ++ks) {
        half8 ah[2], al[2];
        #pragma unroll
        for (int rt = 0; rt < 2; ++rt) {
            int o = swz(rt * 16 + m, ks * 32 + q * 8);
            ah[rt] = *(const half8*)&P0[o];
            al[rt] = *(const half8*)&P1[o];
        }
        int bbase = wv * 13312 + ks * 512 + fb;
        #pragma unroll
        for (int ct = 0; ct < 2; ++ct) {
            half8 bh = *(const half8*)(w1h + bbase + ct * 6656);
            half8 bl = *(const half8*)(w1l + bbase + ct * 6656);
            #pragma unroll
            for (int rt = 0; rt < 2; ++rt) {
                hx[ct][rt] = __builtin_amdgcn_mfma_f32_16x16x32_f16(ah[rt], bh, hx[ct][rt], 0, 0, 0);
                hx[ct][rt] = __builtin_amdgcn_mfma_f32_16x16x32_f16(al[rt], bh, hx[ct][rt], 0, 0, 0);
                hx[ct][rt] = __builtin_amdgcn_mfma_f32_16x16x32_f16(ah[rt], bl, hx[ct][rt], 0, 0, 0);
            }
        }
    }
    __syncthreads();   // all x-plane reads done -> region hosts h planes now

    for (int it = 0; it < 3; ++it) {
        // ===== GEMM1 theta-part: acc = hx + theta @ W1t, K=160 =====
        floatx4 acc[2][2];
        #pragma unroll
        for (int ct = 0; ct < 2; ++ct)
            #pragma unroll
            for (int rt = 0; rt < 2; ++rt) acc[ct][rt] = hx[ct][rt];

        #pragma unroll 1
        for (int ks = 8; ks < 13; ++ks) {
            int kp = (ks - 8) * 32 + q * 8;
            half8 ah[2], al[2];
            #pragma unroll
            for (int rt = 0; rt < 2; ++rt) {
                int o = (rt * 16 + m) * 168 + kp;
                ah[rt] = *(const half8*)&tsh[o];
                al[rt] = *(const half8*)&tsl[o];
            }
            int bbase = wv * 13312 + ks * 512 + fb;
            #pragma unroll
            for (int ct = 0; ct < 2; ++ct) {
                half8 bh = *(const half8*)(w1h + bbase + ct * 6656);
                half8 bl = *(const half8*)(w1l + bbase + ct * 6656);
                #pragma unroll
                for (int rt = 0; rt < 2; ++rt) {
                    acc[ct][rt] = __builtin_amdgcn_mfma_f32_16x16x32_f16(ah[rt], bh, acc[ct][rt], 0, 0, 0);
                    acc[ct][rt] = __builtin_amdgcn_mfma_f32_16x16x32_f16(al[rt], bh, acc[ct][rt], 0, 0, 0);
                    acc[ct][rt] = __builtin_amdgcn_mfma_f32_16x16x32_f16(ah[rt], bl, acc[ct][rt], 0, 0, 0);
                }
            }
        }
        // epi: bias + relu -> h planes (x region; safe: x dead, prev-iter h
        // readers all passed last barrier)
        #pragma unroll
        for (int ct = 0; ct < 2; ++ct) {
            int n = wv * 32 + ct * 16 + m;
            float bv = b1g[n];
            #pragma unroll
            for (int rt = 0; rt < 2; ++rt)
                #pragma unroll
                for (int r = 0; r < 4; ++r) {
                    int row = rt * 16 + q * 4 + r;
                    float v = fmaxf(acc[ct][rt][r] + bv, 0.f);
                    u16 hi, lo; splitf(v, hi, lo);
                    int o = swz(row, n);
                    P0[o] = hi; P1[o] = lo;
                }
        }
        __syncthreads();   // A: h1 visible; all theta reads of this iter done

        // ======== GEMM23: theta += h1 @ (W2@W3) + b23, K=256, N=160(pad) ========
        floatx4 a3[2][2];
        #pragma unroll
        for (int c = 0; c < 2; ++c)
            #pragma unroll
            for (int rt = 0; rt < 2; ++rt) a3[c][rt] = zero4;

        #pragma unroll 2
        for (int ks = 0; ks < 8; ++ks) {
            half8 ah[2], al[2];
            #pragma unroll
            for (int rt = 0; rt < 2; ++rt) {
                int o = swz(rt * 16 + m, ks * 32 + q * 8);
                ah[rt] = *(const half8*)&P0[o];
                al[rt] = *(const half8*)&P1[o];
            }
            int bbase = ks * 512 + fb;
            #pragma unroll
            for (int c = 0; c < 2; ++c) {
                if (c < ncts) {
                    half8 bh = *(const half8*)(w23h + bbase + (wv + c * 8) * 4096);
                    half8 bl = *(const half8*)(w23l + bbase + (wv + c * 8) * 4096);
                    #pragma unroll
                    for (int rt = 0; rt < 2; ++rt) {
                        a3[c][rt] = __builtin_amdgcn_mfma_f32_16x16x32_f16(ah[rt], bh, a3[c][rt], 0, 0, 0);
                        a3[c][rt] = __builtin_amdgcn_mfma_f32_16x16x32_f16(al[rt], bh, a3[c][rt], 0, 0, 0);
                        a3[c][rt] = __builtin_amdgcn_mfma_f32_16x16x32_f16(ah[rt], bl, a3[c][rt], 0, 0, 0);
                    }
                }
            }
        }
        // fp32 residual update of theta master
        #pragma unroll
        for (int c = 0; c < 2; ++c) {
            if (c < ncts) {
                int n3 = (wv + c * 8) * 16 + m;
                float b3v = (n3 < 157) ? b23g[n3] : 0.f;
                #pragma unroll
                for (int rt = 0; rt < 2; ++rt)
                    #pragma unroll
                    for (int r = 0; r < 4; ++r)
                        tm[c][rt][r] += a3[c][rt][r] + b3v;
            }
        }

        if (it < 2) {
            // restage theta (own region; this iter's theta readers finished
            // before sync A)
            #pragma unroll
            for (int c = 0; c < 2; ++c) {
                if (c < ncts) {
                    int n3 = (wv + c * 8) * 16 + m;
                    #pragma unroll
                    for (int rt = 0; rt < 2; ++rt)
                        #pragma unroll
                        for (int r = 0; r < 4; ++r) {
                            int row = rt * 16 + q * 4 + r;
                            u16 hi, lo; splitf(tm[c][rt][r], hi, lo);
                            tsh[row * 168 + n3] = hi;
                            tsl[row * 168 + n3] = lo;
                        }
                }
            }
            __syncthreads();   // B: theta' visible; all GEMM23 h reads done
        } else {
            __syncthreads();   // B: all GEMM23 h reads done -> thf may overlay h
            // final: pose -> fp32 LDS (overlays h planes); betas/camera -> global
            #pragma unroll
            for (int c = 0; c < 2; ++c) {
                if (c < ncts) {
                    int tile = wv + c * 8;
                    int n3 = tile * 16 + m;
                    if (tile < 9) {
                        #pragma unroll
                        for (int rt = 0; rt < 2; ++rt)
                            #pragma unroll
                            for (int r = 0; r < 4; ++r) {
                                int row = rt * 16 + q * 4 + r;
                                thf[row * 144 + n3] = tm[c][rt][r];
                            }
                    } else {  // tile 9: cols 144..159 = betas + camera
                        #pragma unroll
                        for (int rt = 0; rt < 2; ++rt)
                            #pragma unroll
                            for (int r = 0; r < 4; ++r) {
                                int row = rt * 16 + q * 4 + r;
                                long grow = rowbase + row;
                                float v = tm[c][rt][r];
                                if (m < 10)
                                    out[(size_t)NROWS * 216 + grow * 10 + m] = v;
                                else if (m < 13)
                                    out[(size_t)NROWS * 216 + (size_t)NROWS * 10 + grow * 3 + (m - 10)] = v;
                            }
                    }
                }
            }
            __syncthreads();   // thf visible
        }
    }

    // ============ epilogue: rot6d -> rotmat (fp32), 8 threads/row ============
    if (t < 256) {
        int r = t >> 3, g = t & 7;     // 8 threads per row, 3 consecutive joints each
        long grow = rowbase + r;
        #pragma unroll
        for (int jj = 0; jj < 3; ++jj) {
            int j = g * 3 + jj;
            const float* p = &thf[r * 144 + j * 6];
            float a1x = p[0], a2x = p[1], a1y = p[2], a2y = p[3], a1z = p[4], a2z = p[5];
            float n1 = fmaxf(sqrtf(a1x * a1x + a1y * a1y + a1z * a1z), 1e-12f);
            float b1x = a1x / n1, b1y = a1y / n1, b1z = a1z / n1;
            float d = b1x * a2x + b1y * a2y + b1z * a2z;
            float ux = a2x - d * b1x, uy = a2y - d * b1y, uz = a2z - d * b1z;
            float n2 = fmaxf(sqrtf(ux * ux + uy * uy + uz * uz), 1e-12f);
            float b2x = ux / n2, b2y = uy / n2, b2z = uz / n2;
            float b3x = b1y * b2z - b1z * b2y;
            float b3y = b1z * b2x - b1x * b2z;
            float b3z = b1x * b2y - b1y * b2x;
            float* o = out + (size_t)grow * 216 + j * 9;
            o[0] = b1x; o[1] = b2x; o[2] = b3x;
            o[3] = b1y; o[4] = b2y; o[5] = b3y;
            o[6] = b1z; o[7] = b2z; o[8] = b3z;
        }
    }
}

extern "C" void kernel_launch(void* const* d_in, const int* in_sizes, int n_in,
                              void* d_out, int out_size, void* d_ws, size_t ws_size,
                              hipStream_t stream) {
    const float* x  = (const float*)d_in[0];
    const float* W1 = (const float*)d_in[2];
    const float* b1 = (const float*)d_in[3];
    const float* W2 = (const float*)d_in[4];
    const float* b2 = (const float*)d_in[5];
    const float* W3 = (const float*)d_in[6];
    const float* b3 = (const float*)d_in[7];
    const float* ip = (const float*)d_in[8];
    const float* is = (const float*)d_in[9];
    const float* ic = (const float*)d_in[10];

    u16* w1h  = (u16*)d_ws;               // 16 nt * 52 kf * 128 = 106496
    u16* w1l  = w1h + 106496;
    u16* w23h = w1l + 106496;             // 10 nt * 32 kf * 128 = 40960
    u16* w23l = w23h + 40960;
    float* b23f = (float*)(w23l + 40960); // 157 fp32

    prep_pack<<<dim3(4, 16), 256, 0, stream>>>(W1, w1h, w1l, 413, 256, 416);
    prep_w23<<<dim3(2, 10), 256, 0, stream>>>(W2, W3, b2, b3, w23h, w23l, b23f);

    fused_head<<<NROWS / MT, 512, 0, stream>>>(x, w1h, w1l, w23h, w23l,
                                               b1, b23f, ip, is, ic, (float*)d_out);
}

// Round 7
// 590.677 us; speedup vs baseline: 1.5090x; 1.0331x over previous
//
#include <hip/hip_runtime.h>

typedef _Float16 half8 __attribute__((ext_vector_type(8)));
typedef unsigned short ushort8 __attribute__((ext_vector_type(8)));
typedef float floatx4 __attribute__((ext_vector_type(4)));
typedef unsigned short u16;

#define NROWS 115200
#define MT 32

__device__ __forceinline__ void splitf(float f, u16& hi, u16& lo) {
    _Float16 h = (_Float16)f;
    _Float16 l = (_Float16)(f - (float)h);
    hi = __builtin_bit_cast(u16, h);
    lo = __builtin_bit_cast(u16, l);
}

// swizzled index into a [MT][256] fp16 LDS plane (16B-block XOR swizzle)
__device__ __forceinline__ int swz(int row, int col) {
    return row * 256 + ((((col >> 3)) ^ (row & 31)) << 3) + (col & 7);
}

// Merged prep: blocks 0..63 pack W1 (as prep_pack(W1, K=413,N=256,Kd=416)),
// blocks 64..83 compute+pack W23 = W2@W3 and b23 (bit-identical inner math
// to the previous prep_pack / prep_w23 kernels).
__global__ void prep_all(const float* __restrict__ W1, const float* __restrict__ W2,
                         const float* __restrict__ W3, const float* __restrict__ b2,
                         const float* __restrict__ b3,
                         u16* __restrict__ w1h, u16* __restrict__ w1l,
                         u16* __restrict__ w23h, u16* __restrict__ w23l,
                         float* __restrict__ b23) {
    __shared__ float w3c[256][17];   // used only by the w23 path
    int b = blockIdx.x;
    int t = threadIdx.x;

    if (b < 64) {
        // ---- W1 pack: bx = b&3, nt = b>>2; kfrags = 52 ----
        int nt = b >> 2;
        int frag = (b & 3) * 256 + t;
        if (frag >= 52 * 16) return;
        int kf = frag >> 4, m = frag & 15;
        int n = nt * 16 + m;
        ushort8 vh, vl;
        #pragma unroll
        for (int j = 0; j < 8; ++j) {
            int k = kf * 8 + j;
            float v = (k < 413 && n < 256) ? W1[(size_t)k * 256 + n] : 0.f;
            u16 hi, lo; splitf(v, hi, lo);
            vh[j] = hi; vl[j] = lo;
        }
        size_t o = ((size_t)nt * 52 + kf) * 128 + (size_t)m * 8;
        *(ushort8*)&w1h[o] = vh;
        *(ushort8*)&w1l[o] = vl;
        return;
    }

    // ---- W23 path: bb = b-64; bx = bb&1, nt = bb>>1 ----
    int bb = b - 64;
    int bx = bb & 1, nt = bb >> 1;
    #pragma unroll
    for (int c = 0; c < 16; ++c) {
        int n = nt * 16 + c;
        w3c[t][c] = (n < 157) ? W3[(size_t)t * 157 + n] : 0.f;
    }
    __syncthreads();

    int frag = bx * 256 + t;
    int kf = frag >> 4, m = frag & 15;
    int n = nt * 16 + m;

    if (bx == 0 && kf == 0 && n < 157) {
        float bb2 = b3[n];
        for (int j = 0; j < 256; ++j) bb2 = fmaf(b2[j], w3c[j][m], bb2);
        b23[n] = bb2;
    }

    ushort8 vh, vl;
    #pragma unroll
    for (int j = 0; j < 8; ++j) {
        int k = kf * 8 + j;
        const float* w2r = W2 + (size_t)k * 256;
        float acc = 0.f;
        for (int jj = 0; jj < 256; ++jj)
            acc = fmaf(w2r[jj], w3c[jj][m], acc);
        u16 hi, lo; splitf(acc, hi, lo);
        vh[j] = hi; vl[j] = lo;
    }
    size_t o = ((size_t)nt * 32 + kf) * 128 + (size_t)m * 8;
    *(ushort8*)&w23h[o] = vh;
    *(ushort8*)&w23l[o] = vl;
}

// 512 threads = 8 waves; 53KB LDS (512B-granule: 3 x 54272 = 162816 <= 163840
// -> 3 blocks/CU). __launch_bounds__(512,4): measured on this toolchain to cap
// VGPR at exactly 64 (r4: same cap, 2 blocks, 420us with small spill).
// This round isolates "r4 + LDS shrink" -> third resident block.
__global__ __launch_bounds__(512, 4) void fused_head(
    const float* __restrict__ xg,
    const u16* __restrict__ w1h, const u16* __restrict__ w1l,
    const u16* __restrict__ w23h, const u16* __restrict__ w23l,
    const float* __restrict__ b1g, const float* __restrict__ b23g,
    const float* __restrict__ ipose, const float* __restrict__ ishape, const float* __restrict__ icam,
    float* __restrict__ out)
{
    // 54272 B static LDS
    __shared__ __align__(16) u16 smem[27136];
    u16* P0  = smem;                  // x hi plane (prologue) -> h1 hi plane (loop)
    u16* P1  = smem + 8192;           // x lo plane (prologue) -> h1 lo plane (loop)
    u16* tsh = smem + 16384;          // theta hi [32][168]
    u16* tsl = smem + 21760;          // theta lo [32][168]
    float* thf = (float*)smem;        // [32][144] fp32 pose (final; overlays h planes)

    const int t = threadIdx.x;
    const int lid = t & 63, wv = t >> 6;       // 8 waves
    const int q = lid >> 4, m = lid & 15;      // quad, lane-in-16
    const int fb = q * 128 + m * 8;            // fragment-local B offset
    const long rowbase = (long)blockIdx.x * MT;

    // ---- stage x tile (32 rows x 256 fp32 -> split fp16 planes) ----
    #pragma unroll
    for (int i = 0; i < 2; ++i) {
        int idx = t + i * 512;
        int r = idx >> 5, s = idx & 31;
        const float4* sp = (const float4*)(xg + (rowbase + r) * 256 + s * 8);
        float4 f0 = sp[0], f1 = sp[1];
        float fv[8] = {f0.x, f0.y, f0.z, f0.w, f1.x, f1.y, f1.z, f1.w};
        ushort8 vh, vl;
        #pragma unroll
        for (int j = 0; j < 8; ++j) {
            u16 hi, lo; splitf(fv[j], hi, lo);
            vh[j] = hi; vl[j] = lo;
        }
        int o = r * 256 + ((s ^ (r & 31)) << 3);
        *(ushort8*)&P0[o] = vh;
        *(ushort8*)&P1[o] = vl;
    }

    // ---- theta fp32 master in registers (GEMM23 C-frag layout) ----
    // column tile for (wv,c) = wv + c*8; valid tiles 0..9
    const int ncts = (wv < 2) ? 2 : 1;
    float tm[2][2][4];
    #pragma unroll
    for (int c = 0; c < 2; ++c) {
        int n3 = (wv + c * 8) * 16 + m;
        float v;
        if (n3 < 144)      v = ipose[n3];
        else if (n3 < 154) v = ishape[n3 - 144];
        else if (n3 < 157) v = icam[n3 - 154];
        else               v = 0.f;
        #pragma unroll
        for (int rt = 0; rt < 2; ++rt)
            #pragma unroll
            for (int r = 0; r < 4; ++r) tm[c][rt][r] = v;
    }
    // ---- theta0 -> tsh/tsl (disjoint region) ----
    #pragma unroll
    for (int c = 0; c < 2; ++c) {
        if (c < ncts) {
            int n3 = (wv + c * 8) * 16 + m;
            #pragma unroll
            for (int rt = 0; rt < 2; ++rt)
                #pragma unroll
                for (int r = 0; r < 4; ++r) {
                    int row = rt * 16 + q * 4 + r;
                    u16 hi, lo; splitf(tm[c][rt][r], hi, lo);
                    tsh[row * 168 + n3] = hi;
                    tsl[row * 168 + n3] = lo;
                }
        }
    }
    __syncthreads();   // x planes + theta0 visible

    const floatx4 zero4 = {0.f, 0.f, 0.f, 0.f};

    // ============ hoisted: hx = x @ W1x  (K=256, once) ============
    floatx4 hx[2][2];
    #pragma unroll
    for (int ct = 0; ct < 2; ++ct)
        #pragma unroll
        for (int rt = 0; rt < 2; ++rt) hx[ct][rt] = zero4;

    #pragma unroll 2
    for (int ks = 0; ks < 8; ++ks) {
        half8 ah[2], al[2];
        #pragma unroll
        for (int rt = 0; rt < 2; ++rt) {
            int o = swz(rt * 16 + m, ks * 32 + q * 8);
            ah[rt] = *(const half8*)&P0[o];
            al[rt] = *(const half8*)&P1[o];
        }
        int bbase = wv * 13312 + ks * 512 + fb;
        #pragma unroll
        for (int ct = 0; ct < 2; ++ct) {
            half8 bh = *(const half8*)(w1h + bbase + ct * 6656);
            half8 bl = *(const half8*)(w1l + bbase + ct * 6656);
            #pragma unroll
            for (int rt = 0; rt < 2; ++rt) {
                hx[ct][rt] = __builtin_amdgcn_mfma_f32_16x16x32_f16(ah[rt], bh, hx[ct][rt], 0, 0, 0);
                hx[ct][rt] = __builtin_amdgcn_mfma_f32_16x16x32_f16(al[rt], bh, hx[ct][rt], 0, 0, 0);
                hx[ct][rt] = __builtin_amdgcn_mfma_f32_16x16x32_f16(ah[rt], bl, hx[ct][rt], 0, 0, 0);
            }
        }
    }
    __syncthreads();   // all x-plane reads done -> region hosts h planes now

    for (int it = 0; it < 3; ++it) {
        // ===== GEMM1 theta-part: acc = hx + theta @ W1t, K=160 =====
        floatx4 acc[2][2];
        #pragma unroll
        for (int ct = 0; ct < 2; ++ct)
            #pragma unroll
            for (int rt = 0; rt < 2; ++rt) acc[ct][rt] = hx[ct][rt];

        #pragma unroll 1
        for (int ks = 8; ks < 13; ++ks) {
            int kp = (ks - 8) * 32 + q * 8;
            half8 ah[2], al[2];
            #pragma unroll
            for (int rt = 0; rt < 2; ++rt) {
                int o = (rt * 16 + m) * 168 + kp;
                ah[rt] = *(const half8*)&tsh[o];
                al[rt] = *(const half8*)&tsl[o];
            }
            int bbase = wv * 13312 + ks * 512 + fb;
            #pragma unroll
            for (int ct = 0; ct < 2; ++ct) {
                half8 bh = *(const half8*)(w1h + bbase + ct * 6656);
                half8 bl = *(const half8*)(w1l + bbase + ct * 6656);
                #pragma unroll
                for (int rt = 0; rt < 2; ++rt) {
                    acc[ct][rt] = __builtin_amdgcn_mfma_f32_16x16x32_f16(ah[rt], bh, acc[ct][rt], 0, 0, 0);
                    acc[ct][rt] = __builtin_amdgcn_mfma_f32_16x16x32_f16(al[rt], bh, acc[ct][rt], 0, 0, 0);
                    acc[ct][rt] = __builtin_amdgcn_mfma_f32_16x16x32_f16(ah[rt], bl, acc[ct][rt], 0, 0, 0);
                }
            }
        }
        // epi: bias + relu -> h planes (x region; safe: x dead, prev-iter h
        // readers all passed last barrier)
        #pragma unroll
        for (int ct = 0; ct < 2; ++ct) {
            int n = wv * 32 + ct * 16 + m;
            float bv = b1g[n];
            #pragma unroll
            for (int rt = 0; rt < 2; ++rt)
                #pragma unroll
                for (int r = 0; r < 4; ++r) {
                    int row = rt * 16 + q * 4 + r;
                    float v = fmaxf(acc[ct][rt][r] + bv, 0.f);
                    u16 hi, lo; splitf(v, hi, lo);
                    int o = swz(row, n);
                    P0[o] = hi; P1[o] = lo;
                }
        }
        __syncthreads();   // A: h1 visible; all theta reads of this iter done

        // ======== GEMM23: theta += h1 @ (W2@W3) + b23, K=256, N=160(pad) ========
        floatx4 a3[2][2];
        #pragma unroll
        for (int c = 0; c < 2; ++c)
            #pragma unroll
            for (int rt = 0; rt < 2; ++rt) a3[c][rt] = zero4;

        #pragma unroll 2
        for (int ks = 0; ks < 8; ++ks) {
            half8 ah[2], al[2];
            #pragma unroll
            for (int rt = 0; rt < 2; ++rt) {
                int o = swz(rt * 16 + m, ks * 32 + q * 8);
                ah[rt] = *(const half8*)&P0[o];
                al[rt] = *(const half8*)&P1[o];
            }
            int bbase = ks * 512 + fb;
            #pragma unroll
            for (int c = 0; c < 2; ++c) {
                if (c < ncts) {
                    half8 bh = *(const half8*)(w23h + bbase + (wv + c * 8) * 4096);
                    half8 bl = *(const half8*)(w23l + bbase + (wv + c * 8) * 4096);
                    #pragma unroll
                    for (int rt = 0; rt < 2; ++rt) {
                        a3[c][rt] = __builtin_amdgcn_mfma_f32_16x16x32_f16(ah[rt], bh, a3[c][rt], 0, 0, 0);
                        a3[c][rt] = __builtin_amdgcn_mfma_f32_16x16x32_f16(al[rt], bh, a3[c][rt], 0, 0, 0);
                        a3[c][rt] = __builtin_amdgcn_mfma_f32_16x16x32_f16(ah[rt], bl, a3[c][rt], 0, 0, 0);
                    }
                }
            }
        }
        // fp32 residual update of theta master
        #pragma unroll
        for (int c = 0; c < 2; ++c) {
            if (c < ncts) {
                int n3 = (wv + c * 8) * 16 + m;
                float b3v = (n3 < 157) ? b23g[n3] : 0.f;
                #pragma unroll
                for (int rt = 0; rt < 2; ++rt)
                    #pragma unroll
                    for (int r = 0; r < 4; ++r)
                        tm[c][rt][r] += a3[c][rt][r] + b3v;
            }
        }

        if (it < 2) {
            // restage theta (own region; this iter's theta readers finished
            // before sync A)
            #pragma unroll
            for (int c = 0; c < 2; ++c) {
                if (c < ncts) {
                    int n3 = (wv + c * 8) * 16 + m;
                    #pragma unroll
                    for (int rt = 0; rt < 2; ++rt)
                        #pragma unroll
                        for (int r = 0; r < 4; ++r) {
                            int row = rt * 16 + q * 4 + r;
                            u16 hi, lo; splitf(tm[c][rt][r], hi, lo);
                            tsh[row * 168 + n3] = hi;
                            tsl[row * 168 + n3] = lo;
                        }
                }
            }
            __syncthreads();   // B: theta' visible; all GEMM23 h reads done
        } else {
            __syncthreads();   // B: all GEMM23 h reads done -> thf may overlay h
            // final: pose -> fp32 LDS (overlays h planes); betas/camera -> global
            #pragma unroll
            for (int c = 0; c < 2; ++c) {
                if (c < ncts) {
                    int tile = wv + c * 8;
                    int n3 = tile * 16 + m;
                    if (tile < 9) {
                        #pragma unroll
                        for (int rt = 0; rt < 2; ++rt)
                            #pragma unroll
                            for (int r = 0; r < 4; ++r) {
                                int row = rt * 16 + q * 4 + r;
                                thf[row * 144 + n3] = tm[c][rt][r];
                            }
                    } else {  // tile 9: cols 144..159 = betas + camera
                        #pragma unroll
                        for (int rt = 0; rt < 2; ++rt)
                            #pragma unroll
                            for (int r = 0; r < 4; ++r) {
                                int row = rt * 16 + q * 4 + r;
                                long grow = rowbase + row;
                                float v = tm[c][rt][r];
                                if (m < 10)
                                    out[(size_t)NROWS * 216 + grow * 10 + m] = v;
                                else if (m < 13)
                                    out[(size_t)NROWS * 216 + (size_t)NROWS * 10 + grow * 3 + (m - 10)] = v;
                            }
                    }
                }
            }
            __syncthreads();   // thf visible
        }
    }

    // ============ epilogue: rot6d -> rotmat (fp32), 8 threads/row ============
    if (t < 256) {
        int r = t >> 3, g = t & 7;     // 8 threads per row, 3 consecutive joints each
        long grow = rowbase + r;
        #pragma unroll
        for (int jj = 0; jj < 3; ++jj) {
            int j = g * 3 + jj;
            const float* p = &thf[r * 144 + j * 6];
            float a1x = p[0], a2x = p[1], a1y = p[2], a2y = p[3], a1z = p[4], a2z = p[5];
            float n1 = fmaxf(sqrtf(a1x * a1x + a1y * a1y + a1z * a1z), 1e-12f);
            float b1x = a1x / n1, b1y = a1y / n1, b1z = a1z / n1;
            float d = b1x * a2x + b1y * a2y + b1z * a2z;
            float ux = a2x - d * b1x, uy = a2y - d * b1y, uz = a2z - d * b1z;
            float n2 = fmaxf(sqrtf(ux * ux + uy * uy + uz * uz), 1e-12f);
            float b2x = ux / n2, b2y = uy / n2, b2z = uz / n2;
            float b3x = b1y * b2z - b1z * b2y;
            float b3y = b1z * b2x - b1x * b2z;
            float b3z = b1x * b2y - b1y * b2x;
            float* o = out + (size_t)grow * 216 + j * 9;
            o[0] = b1x; o[1] = b2x; o[2] = b3x;
            o[3] = b1y; o[4] = b2y; o[5] = b3y;
            o[6] = b1z; o[7] = b2z; o[8] = b3z;
        }
    }
}

extern "C" void kernel_launch(void* const* d_in, const int* in_sizes, int n_in,
                              void* d_out, int out_size, void* d_ws, size_t ws_size,
                              hipStream_t stream) {
    const float* x  = (const float*)d_in[0];
    const float* W1 = (const float*)d_in[2];
    const float* b1 = (const float*)d_in[3];
    const float* W2 = (const float*)d_in[4];
    const float* b2 = (const float*)d_in[5];
    const float* W3 = (const float*)d_in[6];
    const float* b3 = (const float*)d_in[7];
    const float* ip = (const float*)d_in[8];
    const float* is = (const float*)d_in[9];
    const float* ic = (const float*)d_in[10];

    u16* w1h  = (u16*)d_ws;               // 16 nt * 52 kf * 128 = 106496
    u16* w1l  = w1h + 106496;
    u16* w23h = w1l + 106496;             // 10 nt * 32 kf * 128 = 40960
    u16* w23l = w23h + 40960;
    float* b23f = (float*)(w23l + 40960); // 157 fp32

    prep_all<<<84, 256, 0, stream>>>(W1, W2, W3, b2, b3, w1h, w1l, w23h, w23l, b23f);

    fused_head<<<NROWS / MT, 512, 0, stream>>>(x, w1h, w1l, w23h, w23l,
                                               b1, b23f, ip, is, ic, (float*)d_out);
}